// Round 3
// baseline (1039.972 us; speedup 1.0000x reference)
//
#include <hip/hip_runtime.h>
#include <math.h>

// StressCapsuleLayer: capsule dynamic routing (3 iters), fused recompute design.
//   x [128][648][16] f32, W [648][32][32][16] f32 -> v [128][32][32] f32
//
// 3 passes over (b,n); u_hat recomputed each pass (never materialized).
//   pass0: c = 1/32 exactly            -> s0 -> v0 = squash(s0)
//   pass1: logit = <u_hat, v0>         -> softmax_j -> s1 -> v1
//   pass2: logit = <u,v0> + <u,v1>     -> softmax_j -> s2 -> v2 = output
//
// R2 change: WRITE_SIZE 735MB/pass was scratch spill (u[2][16]+xx[2][16] = 64
// regs of working arrays pushed live set to ~145 > the 128 allocated; ~550B of
// scratch RMW per thread-iter matched WRITE_SIZE exactly). Restructured inner
// loop q-outer/k-inner so x needs only 2 float4 regs (peak live ~115). Also
// XCD-aware block swizzle (NC % 8 == 0, prefer 72): each XCD owns a contiguous
// n-chunk slice so its W slice (~5MB) stays L2-resident across its 8 b-chunks.

#define N_IN 648
#define ELEMS 131072      // 128*32*32 output elements

#define GLDS(gsrc, ldst)                                                        \
  __builtin_amdgcn_global_load_lds(                                             \
      (const __attribute__((address_space(1))) void*)(gsrc),                    \
      (__attribute__((address_space(3))) void*)(ldst), 16, 0, 0)

template <int PHASE>
__global__ __launch_bounds__(256, 2) void caps_pass(
    const float* __restrict__ x,     // [128][648][16]
    const float* __restrict__ W,     // [648][32][32][16]
    const float* __restrict__ v0,    // [128][32][32]  (PHASE>=1)
    const float* __restrict__ v1,    // [128][32][32]  (PHASE==2)
    float* __restrict__ parts,       // [NC][128][32][32] disjoint partial sums
    int NC, int nPer)                // n-chunks, n's per block (648 / NC)
{
  __shared__ float4 wlds[4096];  // 64KB: W[n], chunk c = (k*4+q)*64 + (dblk*32+j)

  const int t = threadIdx.x;
  const int w = t >> 6;   // wave 0..3
  const int l = t & 63;   // lane
  const int j = l & 31;
  const int dblk = l >> 5;

  // XCD-aware decode: round-robin bid->XCD means bid&7 = XCD. Give each XCD a
  // contiguous n-chunk slice (W locality in its private L2). Requires NC%8==0;
  // otherwise fall back to linear decode.
  int nchunk, bchunk;
  {
    const int bid = blockIdx.x;
    if ((NC & 7) == 0) {
      const int ng = NC >> 3;          // n-chunks per XCD
      const int xcd = bid & 7;
      const int rem = bid >> 3;
      nchunk = xcd * ng + (rem % ng);
      bchunk = rem / ng;               // 0..7
    } else {
      nchunk = bid % NC;
      bchunk = bid / NC;
    }
  }
  const int n0 = nchunk * nPer;
  const int b0 = bchunk * 16;

  float s_acc[4][16];
#pragma unroll
  for (int bb = 0; bb < 4; ++bb)
#pragma unroll
    for (int k = 0; k < 16; ++k) s_acc[bb][k] = 0.f;

  for (int nn = 0; nn < nPer; ++nn) {
    const int n = n0 + nn;
    const float4* Wn = (const float4*)(W + (size_t)n * 16384);

    __syncthreads();  // previous iteration's LDS reads complete
#pragma unroll
    for (int r = 0; r < 16; ++r) {
      // physical chunk p = r*256 + t lands at lds + p*16 (linear dest).
      // source quad g = inverse of c(g) = ((k*4+q)*2 + dblk)*32 + j.
      const int p = r * 256 + t;
      const int jj = p & 31;
      const int tt = p >> 5;
      const int db = tt & 1;
      const int kq = tt >> 1;
      const int g = jj * 128 + ((db * 16 + (kq >> 2)) << 2) + (kq & 3);
      GLDS(Wn + g, (char*)wlds + r * 4096 + w * 1024);
    }
    __syncthreads();  // staging drained (vmcnt(0) before barrier)

#pragma unroll
    for (int bbp = 0; bbp < 2; ++bbp) {
      const int b0w = b0 + w * 4 + bbp * 2;
      const float4* xp0 = (const float4*)(x + ((size_t)(b0w + 0) * N_IN + n) * 16);
      const float4* xp1 = (const float4*)(x + ((size_t)(b0w + 1) * N_IN + n) * 16);

      float u[2][16];
#pragma unroll
      for (int k = 0; k < 16; ++k) { u[0][k] = 0.f; u[1][k] = 0.f; }

      // q-outer / k-inner: x held as 2 float4 regs only (no xx[2][16] spill)
#pragma unroll
      for (int q = 0; q < 4; ++q) {
        const float4 xv0 = xp0[q];  // broadcast load (all lanes same addr)
        const float4 xv1 = xp1[q];
#pragma unroll
        for (int k = 0; k < 16; ++k) {
          const float4 wv = wlds[(k * 4 + q) * 64 + l];  // 64-lane contiguous
          u[0][k] = fmaf(wv.x, xv0.x, u[0][k]);
          u[0][k] = fmaf(wv.y, xv0.y, u[0][k]);
          u[0][k] = fmaf(wv.z, xv0.z, u[0][k]);
          u[0][k] = fmaf(wv.w, xv0.w, u[0][k]);
          u[1][k] = fmaf(wv.x, xv1.x, u[1][k]);
          u[1][k] = fmaf(wv.y, xv1.y, u[1][k]);
          u[1][k] = fmaf(wv.z, xv1.z, u[1][k]);
          u[1][k] = fmaf(wv.w, xv1.w, u[1][k]);
        }
      }

#pragma unroll
      for (int h = 0; h < 2; ++h) {
        const int bb = bbp * 2 + h;
        const int b = b0w + h;
        float c;
        if (PHASE == 0) {
          c = 1.0f / 32.0f;  // softmax(zeros) exactly
        } else {
          float logit = 0.f;
          {
            const float4* vp = (const float4*)(v0 + (size_t)b * 1024 + j * 32 + dblk * 16);
            float a = 0.f;
#pragma unroll
            for (int q = 0; q < 4; ++q) {
              const float4 vv = vp[q];
              a = fmaf(u[h][q * 4 + 0], vv.x, a);
              a = fmaf(u[h][q * 4 + 1], vv.y, a);
              a = fmaf(u[h][q * 4 + 2], vv.z, a);
              a = fmaf(u[h][q * 4 + 3], vv.w, a);
            }
            logit += a;
          }
          if (PHASE == 2) {
            const float4* vp = (const float4*)(v1 + (size_t)b * 1024 + j * 32 + dblk * 16);
            float a = 0.f;
#pragma unroll
            for (int q = 0; q < 4; ++q) {
              const float4 vv = vp[q];
              a = fmaf(u[h][q * 4 + 0], vv.x, a);
              a = fmaf(u[h][q * 4 + 1], vv.y, a);
              a = fmaf(u[h][q * 4 + 2], vv.z, a);
              a = fmaf(u[h][q * 4 + 3], vv.w, a);
            }
            logit += a;
          }
          // full agreement over d: combine the two d-halves
          logit += __shfl_xor(logit, 32);
          // softmax over 32 j's (width-32 butterflies; halves are identical)
          float m = logit;
#pragma unroll
          for (int off = 16; off >= 1; off >>= 1) m = fmaxf(m, __shfl_xor(m, off));
          const float e = __expf(logit - m);
          float Z = e;
#pragma unroll
          for (int off = 16; off >= 1; off >>= 1) Z += __shfl_xor(Z, off);
          c = e / Z;
        }
#pragma unroll
        for (int k = 0; k < 16; ++k) s_acc[bb][k] = fmaf(c, u[h][k], s_acc[bb][k]);
      }
    }
  }

  // disjoint partial store: parts[chunk][b][j][d] -- no atomics, no contention
  float* pbase = parts + (size_t)nchunk * ELEMS;
#pragma unroll
  for (int bb = 0; bb < 4; ++bb) {
    const int b = b0 + w * 4 + bb;
    float* sp = pbase + (size_t)b * 1024 + j * 32 + dblk * 16;
#pragma unroll
    for (int k = 0; k < 16; ++k) sp[k] = s_acc[bb][k];
  }
}

// stage B: sum NC partials, then squash over last dim (32) via width-32 shuffle
__global__ void reduce_squash(const float* __restrict__ parts, int NC,
                              float* __restrict__ v) {
  const int e = blockIdx.x * 256 + threadIdx.x;  // rows of 32 align to half-waves
  float s = 0.f;
  for (int c = 0; c < NC; ++c) s += parts[(size_t)c * ELEMS + e];
  float s2 = s * s;
#pragma unroll
  for (int off = 16; off >= 1; off >>= 1) s2 += __shfl_xor(s2, off);
  const float scale = (s2 / (1.0f + s2)) * rsqrtf(s2 + 1e-7f);
  v[e] = s * scale;
}

extern "C" void kernel_launch(void* const* d_in, const int* in_sizes, int n_in,
                              void* d_out, int out_size, void* d_ws, size_t ws_size,
                              hipStream_t stream) {
  const float* x = (const float*)d_in[0];
  const float* W = (const float*)d_in[1];
  float* out = (float*)d_out;

  float* v0 = (float*)d_ws;            // 131072 f32
  float* v1 = v0 + ELEMS;              // 131072 f32
  float* parts = v1 + ELEMS;           // NC * 131072 f32

  // choose NC (divisor of 648) from available workspace; deterministic since
  // ws_size is fixed. Prefer NC%8==0 (XCD-grouped W locality), largest first.
  int avail = 0;
  if (ws_size / 4 > 2 * (size_t)ELEMS)
    avail = (int)((ws_size / 4 - 2 * (size_t)ELEMS) / ELEMS);
  const int ladder[] = {72, 24, 8, 81, 54, 27, 18, 12, 9, 6, 4, 3, 2, 1};
  int NC = 1;
  for (int i = 0; i < 14; ++i)
    if (ladder[i] <= avail) { NC = ladder[i]; break; }
  const int nPer = N_IN / NC;

  const dim3 grid(NC * 8);
  const dim3 blk(256);

  caps_pass<0><<<grid, blk, 0, stream>>>(x, W, nullptr, nullptr, parts, NC, nPer);
  reduce_squash<<<512, 256, 0, stream>>>(parts, NC, v0);

  caps_pass<1><<<grid, blk, 0, stream>>>(x, W, v0, nullptr, parts, NC, nPer);
  reduce_squash<<<512, 256, 0, stream>>>(parts, NC, v1);

  caps_pass<2><<<grid, blk, 0, stream>>>(x, W, v0, v1, parts, NC, nPer);
  reduce_squash<<<512, 256, 0, stream>>>(parts, NC, out);
}